// Round 10
// baseline (254.523 us; speedup 1.0000x reference)
//
#include <hip/hip_runtime.h>

#define TINYF 1e-8f
#define NITER 50
// double-buffered ghost-u store: per buffer 6 blocks x 8 slots x 16 lanes x 4 floats.
// Block W=w+1 slots 0..7 hold wave w's u rows {0,1,2,3,8,9,10,11} (3 cols/lane + pad).
// Blocks W=0 and W=5 stay zero (crop top/bottom edges).
#define GSLOT 64
#define GBLK  (8 * GSLOT)
#define GBUF  (6 * GBLK)

__device__ __forceinline__ float bperm(int addr4, float v) {
    return __int_as_float(__builtin_amdgcn_ds_bpermute(addr4, __float_as_int(v)));
}
// lane i <- lane i-1 within 16-lane DPP row; 0 at row edge (= crop left edge)
__device__ __forceinline__ float dpp_shr1(float v) {
    return __int_as_float(__builtin_amdgcn_update_dpp(0, __float_as_int(v), 0x111, 0xf, 0xf, true));
}
// lane i <- lane i+1 within 16-lane DPP row; 0 at row edge (= crop right edge)
__device__ __forceinline__ float dpp_shl1(float v) {
    return __int_as_float(__builtin_amdgcn_update_dpp(0, __float_as_int(v), 0x101, 0xf, 0xf, true));
}

#define ROWF(C0_, C1_, C2_) \
    L2 = dpp_shr1(C1_); L1 = dpp_shr1(C2_); R1 = dpp_shl1(C0_); R2 = dpp_shl1(C1_); \
    s1a = L1 + C1_; s1b = C0_ + C2_; s1c = C1_ + R1; \
    s2a = L2 + C2_; s2b = L1 + R1; s2c = C0_ + R2;
#define ROWL(C0_, C1_, C2_) \
    L1 = dpp_shr1(C2_); R1 = dpp_shl1(C0_); \
    s1a = L1 + C1_; s1b = C0_ + C2_; s1c = C1_ + R1;
#define ADX(A0_, A1_, A2_, C0_, C1_, C2_, KA, KB, KC) \
    A0_ += KA * C0_ + KB * s1a + KC * s2a; \
    A1_ += KA * C1_ + KB * s1b + KC * s2b; \
    A2_ += KA * C2_ + KB * s1c + KC * s2c;
#define AD2X(A0_, A1_, A2_, C0_, C1_, C2_, KA, KB) \
    A0_ += KA * C0_ + KB * s1a; \
    A1_ += KA * C1_ + KB * s1b; \
    A2_ += KA * C2_ + KB * s1c;

#define CONV_OWN(G, K00,K01,K02,K10,K11,K12,K20,K21) \
  { float L1,L2,R1,R2,s1a,s1b,s1c,s2a,s2b,s2c; \
    acc0=acc1=acc2=acc3=acc4=acc5=acc6=acc7=acc8=0.f; \
    ROWF(G[0], G[1], G[2]) \
    ADX (acc0,acc1,acc2, G[0],G[1],G[2], K00,K01,K02) \
    ADX (acc3,acc4,acc5, G[0],G[1],G[2], K10,K11,K12) \
    AD2X(acc6,acc7,acc8, G[0],G[1],G[2], K20,K21) \
    ROWF(G[3], G[4], G[5]) \
    ADX (acc0,acc1,acc2, G[3],G[4],G[5], K10,K11,K12) \
    ADX (acc3,acc4,acc5, G[3],G[4],G[5], K00,K01,K02) \
    ADX (acc6,acc7,acc8, G[3],G[4],G[5], K10,K11,K12) \
    ROWF(G[6], G[7], G[8]) \
    AD2X(acc0,acc1,acc2, G[6],G[7],G[8], K20,K21) \
    ADX (acc3,acc4,acc5, G[6],G[7],G[8], K10,K11,K12) \
    ADX (acc6,acc7,acc8, G[6],G[7],G[8], K00,K01,K02) \
  }

#define CONV_HALO_R(HA0,HA1,HA2,HB0,HB1,HB2,HC0,HC1,HC2,HD0,HD1,HD2,K10,K11,K12,K20,K21) \
  { float L1,L2,R1,R2,s1a,s1b,s1c,s2a,s2b,s2c; \
    ROWF(HB0,HB1,HB2) \
    ADX (acc0,acc1,acc2, HB0,HB1,HB2, K10,K11,K12) \
    AD2X(acc3,acc4,acc5, HB0,HB1,HB2, K20,K21) \
    ROWL(HA0,HA1,HA2) \
    AD2X(acc0,acc1,acc2, HA0,HA1,HA2, K20,K21) \
    ROWF(HC0,HC1,HC2) \
    AD2X(acc3,acc4,acc5, HC0,HC1,HC2, K20,K21) \
    ADX (acc6,acc7,acc8, HC0,HC1,HC2, K10,K11,K12) \
    ROWL(HD0,HD1,HD2) \
    AD2X(acc6,acc7,acc8, HD0,HD1,HD2, K20,K21) \
  }

__global__ __launch_bounds__(256, 3)
void sinkhorn_ghost(const float* __restrict__ hm_gt,
                    const float* __restrict__ hm_pred,
                    const int* __restrict__ tops,
                    float* __restrict__ out) {
    __shared__ __align__(16) float G0s[GBUF];
    __shared__ __align__(16) float G1s[GBUF];
    __shared__ float sred[8];

    const int t = threadIdx.x;
    const int w = t >> 6;                 // wave: strip rows 12w..12w+11
    const int l = t & 63;
    const int lr = l >> 4, lc = l & 15;   // 4 bands x 16 col-tiles (3 cols each)
    const bool b0 = (lr == 0), b1 = (lr == 1), b2 = (lr == 2), b3 = (lr == 3);
    const bool istop = (lr < 2);
    const bool edge = b0 || b3;

    const int blk = blockIdx.x;
    const int bi = blk / 40, rr = (blk / 5) % 8, cc = blk % 5;
    const int y0 = tops[(bi * 8 + rr) * 2 + 0];
    const int x0 = tops[(bi * 8 + rr) * 2 + 1];
    const float* srcA = hm_gt + (size_t)(bi * 5 + cc) * 25600;
    const float* srcB = hm_pred + (size_t)(bi * 5 + cc) * 25600;

    const int upA = ((l - 16) & 63) << 2;
    const int dnA = ((l + 16) & 63) << 2;
    const int addrXB = b1 ? upA : dnA;    // band1 pulls band0; band2 pulls band3
    const int addrGV = b0 ? dnA : upA;    // band0 pulls band1's gv; band3 pulls band2's

    // ghost-u read: top bands read prev wave's rows 8..11; bottom read next's 0..3
    const int rbase = istop ? (w * 8 + 4) : ((w + 2) * 8 + 0);
    const int roff = rbase * GSLOT + lc * 4;
    // publish: wave w -> block w+1; band slots {0,3,4,5}; edge bands write 3 slots
    const int sfirst = b0 ? 0 : b1 ? 3 : b2 ? 4 : 5;
    const int woff = ((w + 1) * 8 + sfirst) * GSLOT + lc * 4;
    const float* Gr0 = G0s + roff;  float* Gw0 = G0s + woff;
    const float* Gr1 = G1s + roff;  float* Gw1 = G1s + woff;

    // ---- init ghost store: interior blocks = u0, guard blocks = 0 ----
    const float u0 = 1.0f / 2304.0f;
    for (int p = t; p < GBUF; p += 256) {
        const int W = p / GBLK;
        const float val = (W >= 1 && W <= 4) ? u0 : 0.f;
        G0s[p] = val; G1s[p] = val;
    }

    // ---- load 3x3 tiles + ghost-b row; block-reduce sums ----
    const int gr = y0 + 12 * w + 3 * lr;
    const int gc = x0 + 3 * lc;
    float va[9], vb[9], gb0, gb1, gb2;
    float sA = 0.f, sB = 0.f;
#pragma unroll
    for (int i = 0; i < 3; ++i)
#pragma unroll
        for (int c = 0; c < 3; ++c) {
            const float A = srcA[(gr + i) * 160 + gc + c];
            const float B = srcB[(gr + i) * 160 + gc + c];
            va[3 * i + c] = A; vb[3 * i + c] = B;
            sA += A; sB += B;
        }
    {   // ghost row: band -> strip-relative {-2,-1,12,13}
        const int grel = b0 ? -2 : b1 ? -1 : b2 ? 12 : 13;
        const int grow = 12 * w + grel;
        const bool gin = (grow >= 0 && grow < 48);
        const int gg = (y0 + (gin ? grow : 0)) * 160 + gc;
        gb0 = gin ? srcB[gg + 0] : 0.f;
        gb1 = gin ? srcB[gg + 1] : 0.f;
        gb2 = gin ? srcB[gg + 2] : 0.f;
    }
#pragma unroll
    for (int o = 1; o < 64; o <<= 1) {
        sA += __shfl_xor(sA, o, 64);
        sB += __shfl_xor(sB, o, 64);
    }
    if (l == 0) { sred[w] = sA; sred[4 + w] = sB; }
    __syncthreads();   // also covers ghost-store init
    sA = sred[0] + sred[1] + sred[2] + sred[3];
    sB = sred[4] + sred[5] + sred[6] + sred[7];
    const float nA = 1.0f / (sA + TINYF);
    const float nB = 1.0f / (sB + TINYF);
#pragma unroll
    for (int k = 0; k < 9; ++k) { va[k] *= nA; vb[k] *= nB; }
    gb0 *= nB; gb1 *= nB; gb2 *= nB;

    // Gibbs weights (same expressions as R6-R9 -> same rounding)
    const float e10 = expf(-1.0f / 0.1f);
    const float e2  = expf(-sqrtf(2.0f) / 0.1f);
    const float e20 = expf(-2.0f / 0.1f);
    const float e5  = expf(-sqrtf(5.0f) / 0.1f);

    float xu[9], xv[9];
#pragma unroll
    for (int k = 0; k < 9; ++k) xu[k] = u0;

    float acc0, acc1, acc2, acc3, acc4, acc5, acc6, acc7, acc8;

    // ---- one full Sinkhorn iteration: read GRP ghosts, write GWP, 1 barrier ----
    auto iter_body = [&](const float* GRP, float* GWP) {
        // ghost-u reads issued first
        const float4 q0_ = *(const float4*)(GRP);
        const float4 q1_ = *(const float4*)(GRP + GSLOT);
        const float4 q2_ = *(const float4*)(GRP + 2 * GSLOT);
        const float4 q3_ = *(const float4*)(GRP + 3 * GSLOT);
        // phase-1 bperms on u
        const float tA0 = bperm(upA, xu[3]), tA1 = bperm(upA, xu[4]), tA2 = bperm(upA, xu[5]);
        const float tB0 = bperm(upA, xu[6]), tB1 = bperm(upA, xu[7]), tB2 = bperm(upA, xu[8]);
        const float tC0 = bperm(dnA, xu[0]), tC1 = bperm(dnA, xu[1]), tC2 = bperm(dnA, xu[2]);
        const float tD0 = bperm(dnA, xu[3]), tD1 = bperm(dnA, xu[4]), tD2 = bperm(dnA, xu[5]);
        const float xbp0 = istop ? xu[0] : xu[6];
        const float xbp1 = istop ? xu[1] : xu[7];
        const float xbp2 = istop ? xu[2] : xu[8];
        const float XB0 = bperm(addrXB, xbp0), XB1 = bperm(addrXB, xbp1), XB2 = bperm(addrXB, xbp2);

        CONV_OWN(xu, 1.0f, e10, e20, e10, e2, e5, e20, e5)

        const float guA0 = q0_.x, guA1 = q0_.y, guA2 = q0_.z;  // row -4 / 12
        const float guB0 = q1_.x, guB1 = q1_.y, guB2 = q1_.z;  // row -3 / 13
        const float guC0 = q2_.x, guC1 = q2_.y, guC2 = q2_.z;  // row -2 / 14
        const float guD0 = q3_.x, guD1 = q3_.y, guD2 = q3_.z;  // row -1 / 15
        const float hA0 = b0 ? guC0 : tA0, hA1 = b0 ? guC1 : tA1, hA2 = b0 ? guC2 : tA2;
        const float hB0 = b0 ? guD0 : tB0, hB1 = b0 ? guD1 : tB1, hB2 = b0 ? guD2 : tB2;
        const float hC0 = b3 ? guA0 : tC0, hC1 = b3 ? guA1 : tC1, hC2 = b3 ? guA2 : tC2;
        const float hD0 = b3 ? guB0 : tD0, hD1 = b3 ? guB1 : tD1, hD2 = b3 ? guB2 : tD2;
        CONV_HALO_R(hA0,hA1,hA2,hB0,hB1,hB2,hC0,hC1,hC2,hD0,hD1,hD2, e10,e2,e5,e20,e5)

        // ghost-v row (band -> rows {-2,-1,12,13}); window W0..W4 = G-2..G+2
        float g0, g1, g2;
        {
            const float W00 = b0?guA0 : b1?guB0 : b2?hD0 : xu[6];
            const float W01 = b0?guA1 : b1?guB1 : b2?hD1 : xu[7];
            const float W02 = b0?guA2 : b1?guB2 : b2?hD2 : xu[8];
            const float W10 = b0?guB0 : b1?guC0 : b2?XB0 : guA0;
            const float W11 = b0?guB1 : b1?guC1 : b2?XB1 : guA1;
            const float W12 = b0?guB2 : b1?guC2 : b2?XB2 : guA2;
            const float W20 = b0?guC0 : b1?guD0 : b2?guA0 : guB0;
            const float W21 = b0?guC1 : b1?guD1 : b2?guA1 : guB1;
            const float W22 = b0?guC2 : b1?guD2 : b2?guA2 : guB2;
            const float W30 = b0?guD0 : b1?XB0 : b2?guB0 : guC0;
            const float W31 = b0?guD1 : b1?XB1 : b2?guB1 : guC1;
            const float W32 = b0?guD2 : b1?XB2 : b2?guB2 : guC2;
            const float W40 = b0?xu[0] : b1?hA0 : b2?guC0 : guD0;
            const float W41 = b0?xu[1] : b1?hA1 : b2?guC1 : guD1;
            const float W42 = b0?xu[2] : b1?hA2 : b2?guC2 : guD2;
            float L1,L2,R1,R2,s1a,s1b,s1c,s2a,s2b,s2c;
            g0 = g1 = g2 = 0.f;
            ROWL(W00,W01,W02) AD2X(g0,g1,g2, W00,W01,W02, e20,e5)
            ROWF(W10,W11,W12) ADX (g0,g1,g2, W10,W11,W12, e10,e2,e5)
            ROWF(W20,W21,W22) ADX (g0,g1,g2, W20,W21,W22, 1.0f,e10,e20)
            ROWF(W30,W31,W32) ADX (g0,g1,g2, W30,W31,W32, e10,e2,e5)
            ROWL(W40,W41,W42) AD2X(g0,g1,g2, W40,W41,W42, e20,e5)
        }
        const float gv0 = gb0 * __builtin_amdgcn_rcpf(g0 + TINYF);
        const float gv1 = gb1 * __builtin_amdgcn_rcpf(g1 + TINYF);
        const float gv2 = gb2 * __builtin_amdgcn_rcpf(g2 + TINYF);

        xv[0] = vb[0] * __builtin_amdgcn_rcpf(acc0 + TINYF);
        xv[1] = vb[1] * __builtin_amdgcn_rcpf(acc1 + TINYF);
        xv[2] = vb[2] * __builtin_amdgcn_rcpf(acc2 + TINYF);
        xv[3] = vb[3] * __builtin_amdgcn_rcpf(acc3 + TINYF);
        xv[4] = vb[4] * __builtin_amdgcn_rcpf(acc4 + TINYF);
        xv[5] = vb[5] * __builtin_amdgcn_rcpf(acc5 + TINYF);
        xv[6] = vb[6] * __builtin_amdgcn_rcpf(acc6 + TINYF);
        xv[7] = vb[7] * __builtin_amdgcn_rcpf(acc7 + TINYF);
        xv[8] = vb[8] * __builtin_amdgcn_rcpf(acc8 + TINYF);

        // ---- phase 2: v @ K -> u (fully intra-wave) ----
        const float uA0 = bperm(upA, xv[3]), uA1 = bperm(upA, xv[4]), uA2 = bperm(upA, xv[5]);
        const float uB0 = bperm(upA, xv[6]), uB1 = bperm(upA, xv[7]), uB2 = bperm(upA, xv[8]);
        const float uC0 = bperm(dnA, xv[0]), uC1 = bperm(dnA, xv[1]), uC2 = bperm(dnA, xv[2]);
        const float uD0 = bperm(dnA, xv[3]), uD1 = bperm(dnA, xv[4]), uD2 = bperm(dnA, xv[5]);
        const float gvp0 = bperm(addrGV, gv0), gvp1 = bperm(addrGV, gv1), gvp2 = bperm(addrGV, gv2);

        CONV_OWN(xv, 1.0f, e10, e20, e10, e2, e5, e20, e5)

        const float kA0 = b0 ? gv0  : uA0, kA1 = b0 ? gv1  : uA1, kA2 = b0 ? gv2  : uA2;
        const float kB0 = b0 ? gvp0 : uB0, kB1 = b0 ? gvp1 : uB1, kB2 = b0 ? gvp2 : uB2;
        const float kC0 = b3 ? gvp0 : uC0, kC1 = b3 ? gvp1 : uC1, kC2 = b3 ? gvp2 : uC2;
        const float kD0 = b3 ? gv0  : uD0, kD1 = b3 ? gv1  : uD1, kD2 = b3 ? gv2  : uD2;
        CONV_HALO_R(kA0,kA1,kA2,kB0,kB1,kB2,kC0,kC1,kC2,kD0,kD1,kD2, e10,e2,e5,e20,e5)

        xu[0] = va[0] * __builtin_amdgcn_rcpf(acc0 + TINYF);
        xu[1] = va[1] * __builtin_amdgcn_rcpf(acc1 + TINYF);
        xu[2] = va[2] * __builtin_amdgcn_rcpf(acc2 + TINYF);
        xu[3] = va[3] * __builtin_amdgcn_rcpf(acc3 + TINYF);
        xu[4] = va[4] * __builtin_amdgcn_rcpf(acc4 + TINYF);
        xu[5] = va[5] * __builtin_amdgcn_rcpf(acc5 + TINYF);
        xu[6] = va[6] * __builtin_amdgcn_rcpf(acc6 + TINYF);
        xu[7] = va[7] * __builtin_amdgcn_rcpf(acc7 + TINYF);
        xu[8] = va[8] * __builtin_amdgcn_rcpf(acc8 + TINYF);

        // publish boundary u rows to the other buffer
        {
            const float p0 = b2 ? xu[6] : xu[0];
            const float p1 = b2 ? xu[7] : xu[1];
            const float p2 = b2 ? xu[8] : xu[2];
            *(float4*)(GWP) = make_float4(p0, p1, p2, 0.f);
            if (edge) {
                *(float4*)(GWP + GSLOT)     = make_float4(xu[3], xu[4], xu[5], 0.f);
                *(float4*)(GWP + 2 * GSLOT) = make_float4(xu[6], xu[7], xu[8], 0.f);
            }
        }
        __syncthreads();
    };

#pragma unroll 1
    for (int it = 0; it < NITER / 2; ++it) {
        iter_body(Gr0, Gw1);
        iter_body(Gr1, Gw0);
    }

    // ---- loss: (u @ M) . v, M = K .* dist (center 0, corners dropped) ----
    const float s2f = sqrtf(2.0f), s5f = sqrtf(5.0f);
    const float m01 = e10, m02 = e20 * 2.0f, m11 = e2 * s2f, m12 = e5 * s5f;
    {
        const float4 q0_ = *(const float4*)(Gr0);
        const float4 q1_ = *(const float4*)(Gr0 + GSLOT);
        const float4 q2_ = *(const float4*)(Gr0 + 2 * GSLOT);
        const float4 q3_ = *(const float4*)(Gr0 + 3 * GSLOT);
        const float tA0 = bperm(upA, xu[3]), tA1 = bperm(upA, xu[4]), tA2 = bperm(upA, xu[5]);
        const float tB0 = bperm(upA, xu[6]), tB1 = bperm(upA, xu[7]), tB2 = bperm(upA, xu[8]);
        const float tC0 = bperm(dnA, xu[0]), tC1 = bperm(dnA, xu[1]), tC2 = bperm(dnA, xu[2]);
        const float tD0 = bperm(dnA, xu[3]), tD1 = bperm(dnA, xu[4]), tD2 = bperm(dnA, xu[5]);
        CONV_OWN(xu, 0.0f, m01, m02, m01, m11, m12, m02, m12)
        const float hA0 = b0 ? q2_.x : tA0, hA1 = b0 ? q2_.y : tA1, hA2 = b0 ? q2_.z : tA2;
        const float hB0 = b0 ? q3_.x : tB0, hB1 = b0 ? q3_.y : tB1, hB2 = b0 ? q3_.z : tB2;
        const float hC0 = b3 ? q0_.x : tC0, hC1 = b3 ? q0_.y : tC1, hC2 = b3 ? q0_.z : tC2;
        const float hD0 = b3 ? q1_.x : tD0, hD1 = b3 ? q1_.y : tD1, hD2 = b3 ? q1_.z : tD2;
        CONV_HALO_R(hA0,hA1,hA2,hB0,hB1,hB2,hC0,hC1,hC2,hD0,hD1,hD2, m01,m11,m12,m02,m12)
    }
    float lsum = acc0 * xv[0] + acc1 * xv[1] + acc2 * xv[2]
               + acc3 * xv[3] + acc4 * xv[4] + acc5 * xv[5]
               + acc6 * xv[6] + acc7 * xv[7] + acc8 * xv[8];

#pragma unroll
    for (int o = 1; o < 64; o <<= 1) lsum += __shfl_xor(lsum, o, 64);
    if (l == 0) atomicAdd(out, lsum);
}

extern "C" void kernel_launch(void* const* d_in, const int* in_sizes, int n_in,
                              void* d_out, int out_size, void* d_ws, size_t ws_size,
                              hipStream_t stream) {
    (void)in_sizes; (void)n_in; (void)out_size; (void)d_ws; (void)ws_size;
    const float* hm_gt = (const float*)d_in[0];
    const float* hm_pred = (const float*)d_in[1];
    const int* tops = (const int*)d_in[2];
    float* out = (float*)d_out;

    hipMemsetAsync(out, 0, sizeof(float), stream);
    sinkhorn_ghost<<<dim3(640), dim3(256), 0, stream>>>(hm_gt, hm_pred, tops, out);
}

// Round 11
// 233.979 us; speedup vs baseline: 1.0878x; 1.0878x over previous
//
#include <hip/hip_runtime.h>

#define TINYF 1e-8f
#define NITER 50

__device__ __forceinline__ float bperm(int addr4, float v) {
    return __int_as_float(__builtin_amdgcn_ds_bpermute(addr4, __float_as_int(v)));
}
// lane i <- lane i-1 within 16-lane DPP row; 0 at row edge (= crop left edge)
__device__ __forceinline__ float dpp_shr1(float v) {
    return __int_as_float(__builtin_amdgcn_update_dpp(0, __float_as_int(v), 0x111, 0xf, 0xf, true));
}
// lane i <- lane i+1 within 16-lane DPP row; 0 at row edge (= crop right edge)
__device__ __forceinline__ float dpp_shl1(float v) {
    return __int_as_float(__builtin_amdgcn_update_dpp(0, __float_as_int(v), 0x101, 0xf, 0xf, true));
}

// window-row prep over this lane's 3 cols (C0..C2) of one row
#define PREPF(C0_, C1_, C2_) \
    L2 = dpp_shr1(C1_); L1 = dpp_shr1(C2_); R1 = dpp_shl1(C0_); R2 = dpp_shl1(C1_); \
    s1a = L1 + C1_; s1b = C0_ + C2_; s1c = C1_ + R1; \
    s2a = L2 + C2_; s2b = L1 + R1; s2c = C0_ + R2;
#define PREPL(C0_, C1_, C2_) \
    L1 = dpp_shr1(C2_); R1 = dpp_shl1(C0_); \
    s1a = L1 + C1_; s1b = C0_ + C2_; s1c = C1_ + R1;
// |dy|<=1 taps: center + |dx|=1 + |dx|=2
#define A3(I, C0_, C1_, C2_, KA, KB, KC) \
    acc[I][0] += KA * C0_ + KB * s1a + KC * s2a; \
    acc[I][1] += KA * C1_ + KB * s1b + KC * s2b; \
    acc[I][2] += KA * C2_ + KB * s1c + KC * s2c;
// |dy|=2 taps: center + |dx|=1 (corner dropped)
#define A2(I, C0_, C1_, C2_, KA, KB) \
    acc[I][0] += KA * C0_ + KB * s1a; \
    acc[I][1] += KA * C1_ + KB * s1b; \
    acc[I][2] += KA * C2_ + KB * s1c;

__global__ __launch_bounds__(64, 1)
void sinkhorn_reg(const float* __restrict__ hm_gt,
                  const float* __restrict__ hm_pred,
                  const int* __restrict__ tops,
                  float* __restrict__ out) {
    const int l = threadIdx.x;
    const int b = l >> 4, c = l & 15;      // band (12 rows) x colgroup (3 cols)
    const bool b0 = (b == 0), b3 = (b == 3);
    const int upA = ((l - 16) & 63) << 2;
    const int dnA = ((l + 16) & 63) << 2;

    const int blk = blockIdx.x;            // ((bi*8+rr)*5+cc)
    const int bi = blk / 40, rr = (blk / 5) % 8, cc = blk % 5;
    const int y0 = tops[(bi * 8 + rr) * 2 + 0];
    const int x0 = tops[(bi * 8 + rr) * 2 + 1];
    const float* srcA = hm_gt + (size_t)(bi * 5 + cc) * 25600;
    const float* srcB = hm_pred + (size_t)(bi * 5 + cc) * 25600;

    // ---- load own 12x3 tiles of both crops; wave-reduce sums ----
    float va[12][3], vb[12][3];
    float sA = 0.f, sB = 0.f;
#pragma unroll
    for (int i = 0; i < 12; ++i) {
        const int g = (y0 + 12 * b + i) * 160 + x0 + 3 * c;
#pragma unroll
        for (int j = 0; j < 3; ++j) {
            const float A = srcA[g + j];
            const float B = srcB[g + j];
            va[i][j] = A; vb[i][j] = B;
            sA += A; sB += B;
        }
    }
#pragma unroll
    for (int o = 1; o < 64; o <<= 1) {
        sA += __shfl_xor(sA, o, 64);
        sB += __shfl_xor(sB, o, 64);
    }
    const float nA = 1.0f / (sA + TINYF);
    const float nB = 1.0f / (sB + TINYF);
#pragma unroll
    for (int i = 0; i < 12; ++i)
#pragma unroll
        for (int j = 0; j < 3; ++j) { va[i][j] *= nA; vb[i][j] *= nB; }

    // Gibbs weights (same expressions as R6-R10 -> same rounding)
    const float e10 = expf(-1.0f / 0.1f);
    const float e2  = expf(-sqrtf(2.0f) / 0.1f);
    const float e20 = expf(-2.0f / 0.1f);
    const float e5  = expf(-sqrtf(5.0f) / 0.1f);

    float xu[12][3], xv[12][3], acc[12][3];
    const float u0 = 1.0f / 2304.0f;
#pragma unroll
    for (int i = 0; i < 12; ++i)
#pragma unroll
        for (int j = 0; j < 3; ++j) xu[i][j] = u0;

    // 21-tap 5x5 conv, fully intra-wave: vertical halos via 12 bperms (no sync),
    // horizontal via DPP (bound_ctrl zeroes = crop edges).
    auto conv = [&](const float (&x)[12][3],
                    float K00, float K01, float K02,
                    float K10, float K11, float K12,
                    float K20, float K21) {
        float hA[3], hB[3], hC[3], hD[3];   // rows -2,-1,12,13
#pragma unroll
        for (int j = 0; j < 3; ++j) {
            const float a_ = bperm(upA, x[10][j]);
            const float bb_ = bperm(upA, x[11][j]);
            const float c_ = bperm(dnA, x[0][j]);
            const float d_ = bperm(dnA, x[1][j]);
            hA[j] = b0 ? 0.f : a_;
            hB[j] = b0 ? 0.f : bb_;
            hC[j] = b3 ? 0.f : c_;
            hD[j] = b3 ? 0.f : d_;
        }
#pragma unroll
        for (int i = 0; i < 12; ++i)
#pragma unroll
            for (int j = 0; j < 3; ++j) acc[i][j] = 0.f;

        float L1, L2, R1, R2, s1a, s1b, s1c, s2a, s2b, s2c;
        // own window rows 0..11 first (no DS dependence -> hides bperm latency)
#pragma unroll
        for (int w = 0; w < 12; ++w) {
            PREPF(x[w][0], x[w][1], x[w][2])
            if (w >= 2)  { A2(w - 2, x[w][0], x[w][1], x[w][2], K20, K21) }
            if (w >= 1)  { A3(w - 1, x[w][0], x[w][1], x[w][2], K10, K11, K12) }
            { A3(w, x[w][0], x[w][1], x[w][2], K00, K01, K02) }
            if (w <= 10) { A3(w + 1, x[w][0], x[w][1], x[w][2], K10, K11, K12) }
            if (w <= 9)  { A2(w + 2, x[w][0], x[w][1], x[w][2], K20, K21) }
        }
        // halo rows (consume bperm results last)
        PREPF(hB[0], hB[1], hB[2])          // row -1
        { A3(0, hB[0], hB[1], hB[2], K10, K11, K12) }
        { A2(1, hB[0], hB[1], hB[2], K20, K21) }
        PREPL(hA[0], hA[1], hA[2])          // row -2
        { A2(0, hA[0], hA[1], hA[2], K20, K21) }
        PREPF(hC[0], hC[1], hC[2])          // row 12
        { A2(10, hC[0], hC[1], hC[2], K20, K21) }
        { A3(11, hC[0], hC[1], hC[2], K10, K11, K12) }
        PREPL(hD[0], hD[1], hD[2])          // row 13
        { A2(11, hD[0], hD[1], hD[2], K20, K21) }
    };

    // ---- Sinkhorn iterations: no LDS, no barriers ----
#pragma unroll 1
    for (int it = 0; it < NITER; ++it) {
        conv(xu, 1.0f, e10, e20, e10, e2, e5, e20, e5);
#pragma unroll
        for (int i = 0; i < 12; ++i)
#pragma unroll
            for (int j = 0; j < 3; ++j)
                xv[i][j] = vb[i][j] * __builtin_amdgcn_rcpf(acc[i][j] + TINYF);

        conv(xv, 1.0f, e10, e20, e10, e2, e5, e20, e5);
#pragma unroll
        for (int i = 0; i < 12; ++i)
#pragma unroll
            for (int j = 0; j < 3; ++j)
                xu[i][j] = va[i][j] * __builtin_amdgcn_rcpf(acc[i][j] + TINYF);
    }

    // ---- loss: (u @ M) . v, M = K .* dist (center 0, corners dropped) ----
    const float s2f = sqrtf(2.0f), s5f = sqrtf(5.0f);
    const float m01 = e10, m02 = e20 * 2.0f, m11 = e2 * s2f, m12 = e5 * s5f;
    conv(xu, 0.0f, m01, m02, m01, m11, m12, m02, m12);
    float lsum = 0.f;
#pragma unroll
    for (int i = 0; i < 12; ++i)
#pragma unroll
        for (int j = 0; j < 3; ++j)
            lsum += acc[i][j] * xv[i][j];

#pragma unroll
    for (int o = 1; o < 64; o <<= 1) lsum += __shfl_xor(lsum, o, 64);
    if (l == 0) atomicAdd(out, lsum);
}

extern "C" void kernel_launch(void* const* d_in, const int* in_sizes, int n_in,
                              void* d_out, int out_size, void* d_ws, size_t ws_size,
                              hipStream_t stream) {
    (void)in_sizes; (void)n_in; (void)out_size; (void)d_ws; (void)ws_size;
    const float* hm_gt = (const float*)d_in[0];
    const float* hm_pred = (const float*)d_in[1];
    const int* tops = (const int*)d_in[2];
    float* out = (float*)d_out;

    hipMemsetAsync(out, 0, sizeof(float), stream);
    sinkhorn_reg<<<dim3(640), dim3(64), 0, stream>>>(hm_gt, hm_pred, tops, out);
}

// Round 12
// 224.066 us; speedup vs baseline: 1.1359x; 1.0442x over previous
//
#include <hip/hip_runtime.h>

#define TINYF 1e-8f
#define NITER 50

__device__ __forceinline__ float bperm(int addr4, float v) {
    return __int_as_float(__builtin_amdgcn_ds_bpermute(addr4, __float_as_int(v)));
}
// lane i <- lane i-1 within 16-lane DPP row; 0 at row edge (= crop left edge)
__device__ __forceinline__ float dpp_shr1(float v) {
    return __int_as_float(__builtin_amdgcn_update_dpp(0, __float_as_int(v), 0x111, 0xf, 0xf, true));
}
// lane i <- lane i+1 within 16-lane DPP row; 0 at row edge (= crop right edge)
__device__ __forceinline__ float dpp_shl1(float v) {
    return __int_as_float(__builtin_amdgcn_update_dpp(0, __float_as_int(v), 0x101, 0xf, 0xf, true));
}

#define PREPF(C0_, C1_, C2_) \
    L2 = dpp_shr1(C1_); L1 = dpp_shr1(C2_); R1 = dpp_shl1(C0_); R2 = dpp_shl1(C1_); \
    s1a = L1 + C1_; s1b = C0_ + C2_; s1c = C1_ + R1; \
    s2a = L2 + C2_; s2b = L1 + R1; s2c = C0_ + R2;
#define PREPL(C0_, C1_, C2_) \
    L1 = dpp_shr1(C2_); R1 = dpp_shl1(C0_); \
    s1a = L1 + C1_; s1b = C0_ + C2_; s1c = C1_ + R1;
#define A3(I, C0_, C1_, C2_, KA, KB, KC) \
    acc[I][0] += KA * C0_ + KB * s1a + KC * s2a; \
    acc[I][1] += KA * C1_ + KB * s1b + KC * s2b; \
    acc[I][2] += KA * C2_ + KB * s1c + KC * s2c;
#define A2(I, C0_, C1_, C2_, KA, KB) \
    acc[I][0] += KA * C0_ + KB * s1a; \
    acc[I][1] += KA * C1_ + KB * s1b; \
    acc[I][2] += KA * C2_ + KB * s1c;

// EX layout (floats): [parity(2)][side(2)][row(2)][lane16][4]
// side0 = crop rows 22,23 (written by wave0 band3); side1 = rows 24,25 (wave1 band0).
__global__ __launch_bounds__(128, 2)
void sinkhorn_half(const float* __restrict__ hm_gt,
                   const float* __restrict__ hm_pred,
                   const int* __restrict__ tops,
                   float* __restrict__ out) {
    __shared__ __align__(16) float EX[2 * 512];
    __shared__ float sred[4];

    const int t = threadIdx.x;
    const int W = t >> 6;                  // wave 0: rows 0-23; wave 1: rows 24-47
    const int l = t & 63;
    const int b = l >> 4, c = l & 15;      // band (6 rows) x colgroup (3 cols)
    const bool btop = (b == 0), bbot = (b == 3);
    const bool xchg = (W == 0) ? bbot : btop;   // lanes on the inter-wave boundary
    const int upA = ((l - 16) & 63) << 2;
    const int dnA = ((l + 16) & 63) << 2;

    const int blk = blockIdx.x;            // ((bi*8+rr)*5+cc)
    const int bi = blk / 40, rr = (blk / 5) % 8, cc = blk % 5;
    const int y0 = tops[(bi * 8 + rr) * 2 + 0];
    const int x0 = tops[(bi * 8 + rr) * 2 + 1];
    const float* srcA = hm_gt + (size_t)(bi * 5 + cc) * 25600;
    const float* srcB = hm_pred + (size_t)(bi * 5 + cc) * 25600;

    // exchange pointers (parity adds +512 floats)
    float* wp = EX + W * 256 + c * 4;           // own side
    const float* rp = EX + (1 - W) * 256 + c * 4;

    // ---- load own 6x3 tiles of both crops; block-reduce sums ----
    float va[6][3], vb[6][3];
    float sA = 0.f, sB = 0.f;
    const int rbase = y0 + 24 * W + 6 * b;
#pragma unroll
    for (int i = 0; i < 6; ++i) {
        const int g = (rbase + i) * 160 + x0 + 3 * c;
#pragma unroll
        for (int j = 0; j < 3; ++j) {
            const float A = srcA[g + j];
            const float B = srcB[g + j];
            va[i][j] = A; vb[i][j] = B;
            sA += A; sB += B;
        }
    }
#pragma unroll
    for (int o = 1; o < 64; o <<= 1) {
        sA += __shfl_xor(sA, o, 64);
        sB += __shfl_xor(sB, o, 64);
    }
    if (l == 0) { sred[W] = sA; sred[2 + W] = sB; }
    __syncthreads();
    sA = sred[0] + sred[1];
    sB = sred[2] + sred[3];
    const float nA = 1.0f / (sA + TINYF);
    const float nB = 1.0f / (sB + TINYF);
#pragma unroll
    for (int i = 0; i < 6; ++i)
#pragma unroll
        for (int j = 0; j < 3; ++j) { va[i][j] *= nA; vb[i][j] *= nB; }

    // Gibbs weights (same expressions as R6-R11 -> same rounding)
    const float e10 = expf(-1.0f / 0.1f);
    const float e2  = expf(-sqrtf(2.0f) / 0.1f);
    const float e20 = expf(-2.0f / 0.1f);
    const float e5  = expf(-sqrtf(5.0f) / 0.1f);

    float xu[6][3], xv[6][3], acc[6][3];
    const float u0 = 1.0f / 2304.0f;
#pragma unroll
    for (int i = 0; i < 6; ++i)
#pragma unroll
        for (int j = 0; j < 3; ++j) xu[i][j] = u0;

    // publish u0 boundary rows into parity-0 buffer
    if (xchg) {
        *(float4*)(wp)      = make_float4(u0, u0, u0, 0.f);
        *(float4*)(wp + 64) = make_float4(u0, u0, u0, 0.f);
    }
    __syncthreads();

    // 21-tap 5x5 conv over this wave's 24-row strip. Vertical halos: intra-wave
    // bperm for band boundaries; LDS (parity poffR) for the inter-wave boundary;
    // zeros at crop top/bottom. Horizontal: DPP bound_ctrl zero = crop edges.
    auto conv = [&](const float (&x)[6][3], int poffR,
                    float K00, float K01, float K02,
                    float K10, float K11, float K12,
                    float K20, float K21) {
        float4 q0 = make_float4(0.f, 0.f, 0.f, 0.f), q1 = q0;
        if (xchg) {
            q0 = *(const float4*)(rp + poffR);
            q1 = *(const float4*)(rp + poffR + 64);
        }
        float tA[3], tB[3], tC[3], tD[3];
#pragma unroll
        for (int j = 0; j < 3; ++j) {
            tA[j] = bperm(upA, x[4][j]);   // row -2 candidate
            tB[j] = bperm(upA, x[5][j]);   // row -1
            tC[j] = bperm(dnA, x[0][j]);   // row  6
            tD[j] = bperm(dnA, x[1][j]);   // row  7
        }
#pragma unroll
        for (int i = 0; i < 6; ++i)
#pragma unroll
            for (int j = 0; j < 3; ++j) acc[i][j] = 0.f;

        float L1, L2, R1, R2, s1a, s1b, s1c, s2a, s2b, s2c;
        // own rows first (no DS dependence -> hides bperm/LDS latency)
#pragma unroll
        for (int w = 0; w < 6; ++w) {
            PREPF(x[w][0], x[w][1], x[w][2])
            if (w >= 2) { A2(w - 2, x[w][0], x[w][1], x[w][2], K20, K21) }
            if (w >= 1) { A3(w - 1, x[w][0], x[w][1], x[w][2], K10, K11, K12) }
            { A3(w, x[w][0], x[w][1], x[w][2], K00, K01, K02) }
            if (w <= 4) { A3(w + 1, x[w][0], x[w][1], x[w][2], K10, K11, K12) }
            if (w <= 3) { A2(w + 2, x[w][0], x[w][1], x[w][2], K20, K21) }
        }
        // resolve halos
        float hA[3], hB[3], hC[3], hD[3];
        const float qv0[3] = {q0.x, q0.y, q0.z};
        const float qv1[3] = {q1.x, q1.y, q1.z};
#pragma unroll
        for (int j = 0; j < 3; ++j) {
            if (W == 0) {
                hA[j] = btop ? 0.f : tA[j];
                hB[j] = btop ? 0.f : tB[j];
                hC[j] = bbot ? qv0[j] : tC[j];
                hD[j] = bbot ? qv1[j] : tD[j];
            } else {
                hA[j] = btop ? qv0[j] : tA[j];
                hB[j] = btop ? qv1[j] : tB[j];
                hC[j] = bbot ? 0.f : tC[j];
                hD[j] = bbot ? 0.f : tD[j];
            }
        }
        // halo-row contributions
        PREPF(hB[0], hB[1], hB[2])          // row -1
        { A3(0, hB[0], hB[1], hB[2], K10, K11, K12) }
        { A2(1, hB[0], hB[1], hB[2], K20, K21) }
        PREPL(hA[0], hA[1], hA[2])          // row -2
        { A2(0, hA[0], hA[1], hA[2], K20, K21) }
        PREPF(hC[0], hC[1], hC[2])          // row 6
        { A2(4, hC[0], hC[1], hC[2], K20, K21) }
        { A3(5, hC[0], hC[1], hC[2], K10, K11, K12) }
        PREPL(hD[0], hD[1], hD[2])          // row 7
        { A2(5, hD[0], hD[1], hD[2], K20, K21) }
    };

    // publish boundary rows of field y into parity buffer poffW, then sync
    auto publish = [&](const float (&y)[6][3], int poffW) {
        if (xchg) {
            const int r0 = (W == 0) ? 4 : 0;
            *(float4*)(wp + poffW)      = make_float4(y[r0][0], y[r0][1], y[r0][2], 0.f);
            *(float4*)(wp + poffW + 64) = make_float4(y[r0+1][0], y[r0+1][1], y[r0+1][2], 0.f);
        }
        __syncthreads();
    };

    // ---- Sinkhorn iterations: 1 barrier per half-iteration on a 2-wave block ----
#pragma unroll 1
    for (int it = 0; it < NITER; ++it) {
        conv(xu, 0, 1.0f, e10, e20, e10, e2, e5, e20, e5);
#pragma unroll
        for (int i = 0; i < 6; ++i)
#pragma unroll
            for (int j = 0; j < 3; ++j)
                xv[i][j] = vb[i][j] * __builtin_amdgcn_rcpf(acc[i][j] + TINYF);
        publish(xv, 512);

        conv(xv, 512, 1.0f, e10, e20, e10, e2, e5, e20, e5);
#pragma unroll
        for (int i = 0; i < 6; ++i)
#pragma unroll
            for (int j = 0; j < 3; ++j)
                xu[i][j] = va[i][j] * __builtin_amdgcn_rcpf(acc[i][j] + TINYF);
        publish(xu, 0);
    }

    // ---- loss: (u @ M) . v, M = K .* dist (center 0, corners dropped) ----
    const float s2f = sqrtf(2.0f), s5f = sqrtf(5.0f);
    const float m01 = e10, m02 = e20 * 2.0f, m11 = e2 * s2f, m12 = e5 * s5f;
    conv(xu, 0, 0.0f, m01, m02, m01, m11, m12, m02, m12);
    float lsum = 0.f;
#pragma unroll
    for (int i = 0; i < 6; ++i)
#pragma unroll
        for (int j = 0; j < 3; ++j)
            lsum += acc[i][j] * xv[i][j];

#pragma unroll
    for (int o = 1; o < 64; o <<= 1) lsum += __shfl_xor(lsum, o, 64);
    if (l == 0) sred[W] = lsum;
    __syncthreads();
    if (t == 0) atomicAdd(out, sred[0] + sred[1]);
}

extern "C" void kernel_launch(void* const* d_in, const int* in_sizes, int n_in,
                              void* d_out, int out_size, void* d_ws, size_t ws_size,
                              hipStream_t stream) {
    (void)in_sizes; (void)n_in; (void)out_size; (void)d_ws; (void)ws_size;
    const float* hm_gt = (const float*)d_in[0];
    const float* hm_pred = (const float*)d_in[1];
    const int* tops = (const int*)d_in[2];
    float* out = (float*)d_out;

    hipMemsetAsync(out, 0, sizeof(float), stream);
    sinkhorn_half<<<dim3(640), dim3(128), 0, stream>>>(hm_gt, hm_pred, tops, out);
}